// Round 1
// baseline (60.214 us; speedup 1.0000x reference)
//
#include <hip/hip_runtime.h>
#include <hip/hip_bf16.h>

// Causal depthwise conv1d (K=4) + SiLU over x:(B,S,D) fp32, w:(D,1,4) fp32.
// y[b,s,d] = silu(w[d,0]*x[s-3,d] + w[d,1]*x[s-2,d] + w[d,2]*x[s-1,d] + w[d,3]*x[s,d])
// Memory-bound: thread = one float4 channel group x TS consecutive s positions,
// sliding window in registers.

#define TS 8  // s-positions per thread; read amplification (TS+3)/TS = 1.375

__global__ __launch_bounds__(256) void causal_conv1d_silu_kernel(
    const float4* __restrict__ x,   // (B,S,D/4) float4
    const float4* __restrict__ w4,  // (D,) float4: w4[d] = weights k=0..3 of channel d
    float4* __restrict__ y,
    int B, int S, int D4)           // D4 = D/4
{
    const int t = blockIdx.x * blockDim.x + threadIdx.x;
    const int n_stiles = S / TS;
    const int d4 = t % D4;
    const int rest = t / D4;
    if (rest >= B * n_stiles) return;
    const int stile = rest % n_stiles;
    const int b = rest / n_stiles;
    const int s0 = stile * TS;

    // 16 weights for channels d = 4*d4 .. 4*d4+3 (w is (D,4) row-major in fp32)
    const float4 wa = w4[d4 * 4 + 0];  // channel 4*d4+0, taps k=0..3
    const float4 wb = w4[d4 * 4 + 1];
    const float4 wc = w4[d4 * 4 + 2];
    const float4 wd = w4[d4 * 4 + 3];

    const size_t base = (size_t)b * S * D4 + d4;
    const float4* xp = x + base;
    float4* yp = y + base;

    const float4 zero = make_float4(0.f, 0.f, 0.f, 0.f);
    float4 xm3 = (s0 >= 3) ? xp[(size_t)(s0 - 3) * D4] : zero;
    float4 xm2 = (s0 >= 2) ? xp[(size_t)(s0 - 2) * D4] : zero;
    float4 xm1 = (s0 >= 1) ? xp[(size_t)(s0 - 1) * D4] : zero;

#pragma unroll
    for (int i = 0; i < TS; ++i) {
        const float4 xc = xp[(size_t)(s0 + i) * D4];
        float4 o;
        o.x = wa.x * xm3.x + wa.y * xm2.x + wa.z * xm1.x + wa.w * xc.x;
        o.y = wb.x * xm3.y + wb.y * xm2.y + wb.z * xm1.y + wb.w * xc.y;
        o.z = wc.x * xm3.z + wc.y * xm2.z + wc.z * xm1.z + wc.w * xc.z;
        o.w = wd.x * xm3.w + wd.y * xm2.w + wd.z * xm1.w + wd.w * xc.w;
        // SiLU: v * sigmoid(v) = v / (1 + exp(-v))
        o.x = o.x / (1.f + __expf(-o.x));
        o.y = o.y / (1.f + __expf(-o.y));
        o.z = o.z / (1.f + __expf(-o.z));
        o.w = o.w / (1.f + __expf(-o.w));
        yp[(size_t)(s0 + i) * D4] = o;
        xm3 = xm2; xm2 = xm1; xm1 = xc;
    }
}

extern "C" void kernel_launch(void* const* d_in, const int* in_sizes, int n_in,
                              void* d_out, int out_size, void* d_ws, size_t ws_size,
                              hipStream_t stream) {
    const float* x = (const float*)d_in[0];
    const float* w = (const float*)d_in[1];
    float* y = (float*)d_out;

    // x: (B, S, D) = (4, 4096, 2048); w: (D, 1, 4)
    const int D = in_sizes[1] / 4;     // 2048
    const int D4 = D / 4;              // 512
    const int BS = in_sizes[0] / D;    // B*S = 16384
    const int S = 4096;
    const int B = BS / S;              // 4

    const int n_stiles = S / TS;
    const long long total_threads = (long long)B * n_stiles * D4;
    const int block = 256;
    const int grid = (int)((total_threads + block - 1) / block);

    causal_conv1d_silu_kernel<<<grid, block, 0, stream>>>(
        (const float4*)x, (const float4*)w, (float4*)y, B, S, D4);
}